// Round 5
// baseline (237.914 us; speedup 1.0000x reference)
//
#include <hip/hip_runtime.h>
#include <math.h>

#define DEV __device__ __forceinline__

// Packed fp32 pair: .x = row A, .y = row B -> v_pk_fma_f32 (2 rows/inst).
typedef float f2 __attribute__((ext_vector_type(2)));

DEV f2 splat(float s) { f2 r; r.x = s; r.y = s; return r; }

// R5: single-base weight stream.
//
// R4 post-mortem: o-tile SGPR merge helped only 75->70us; busy/wave 6.2k cyc
// (1.31x pk_fma floor) but wait/wave ~26k cyc -> weight-stream LATENCY
// exposure, not transaction count. Causes: 29 arg pointers pin ~58 SGPRs
// (budget 112 maxed -> no prefetch headroom) and 28 disjoint bases defeat
// stream scheduling.
//
// Fix: repack kernel (1 block, 1324 floats) concatenates weights+biases into
// ONE 16B-aligned __device__ buffer in consumption order, each segment padded
// to 4-float alignment. Main kernel: one scalar base, every access
// base+constexpr-imm -> s_load_dwordx8/x16 merges, ~70 SGPRs free for 2-3
// tiles of prefetch, monotone scalar stream. FMA structure identical to R4
// (pair+pk, o-tile 4, k ascending) -> numerics unchanged.

// Packed layout offsets (floats); every segment 4-float (16 B) aligned.
#define OW1  0
#define OB1  144
#define OW2  156
#define OB2  288
#define OW3  300
#define OB3  412
#define OW4  424
#define OB4  516
#define OW5  528
#define OB5  600
#define OW6  608
#define OB6  664
#define OW7  672
#define OB7  716
#define OW8  724
#define OB8  768
#define OW9  776
#define OB9  832
#define OW10 840
#define OB10 912
#define OW11 924
#define OB11 1016
#define OW12 1028
#define OB12 1140
#define OW13 1152
#define OB13 1284
#define OW14 1296
#define OB14 1320
#define WTOT 1324

__device__ __attribute__((aligned(16))) float Wpack[WTOT];

__global__ void repack_kernel(
    const float* w1,  const float* b1,  const float* w2,  const float* b2,
    const float* w3,  const float* b3,  const float* w4,  const float* b4,
    const float* w5,  const float* b5,  const float* w6,  const float* b6,
    const float* w7,  const float* b7,  const float* w8,  const float* b8,
    const float* w9,  const float* b9,  const float* w10, const float* b10,
    const float* w11, const float* b11, const float* w12, const float* b12,
    const float* w13, const float* b13, const float* w14, const float* b14) {
    struct Seg { const float* src; int dst; int len; };
    const Seg segs[28] = {
        {w1,  OW1,  144}, {b1,  OB1,  12}, {w2,  OW2,  132}, {b2,  OB2,  11},
        {w3,  OW3,  110}, {b3,  OB3,  10}, {w4,  OW4,   90}, {b4,  OB4,   9},
        {w5,  OW5,   72}, {b5,  OB5,   8}, {w6,  OW6,   56}, {b6,  OB6,   7},
        {w7,  OW7,   42}, {b7,  OB7,   6}, {w8,  OW8,   42}, {b8,  OB8,   7},
        {w9,  OW9,   56}, {b9,  OB9,   8}, {w10, OW10,  72}, {b10, OB10,  9},
        {w11, OW11,  90}, {b11, OB11, 10}, {w12, OW12, 110}, {b12, OB12, 11},
        {w13, OW13, 132}, {b13, OB13, 12}, {w14, OW14,  24}, {b14, OB14,  2}};
    const int tid = threadIdx.x;
    for (int s = 0; s < 28; ++s)
        for (int i = tid; i < segs[s].len; i += 256)
            Wpack[segs[s].dst + i] = segs[s].src[i];
}

// o-TILE (4 rows) + k-inner, weights from the packed stream.
template <int DIN, int DOUT, int WO, int BO>
DEV void lin2(const f2* in, f2* out) {
    const float* __restrict__ w =
        (const float*)__builtin_assume_aligned(&Wpack[WO], 16);
    const float* __restrict__ b = &Wpack[BO];
#pragma unroll
    for (int ot = 0; ot < DOUT; ot += 4) {
        const int oe = (ot + 4 < DOUT) ? (ot + 4) : DOUT;
        float wt[48];
#pragma unroll
        for (int i = 0; i < 48; ++i) {
            if (i < (oe - ot) * DIN) wt[i] = w[ot * DIN + i];
        }
#pragma unroll
        for (int o = ot; o < oe; ++o) out[o] = splat(b[o]);
#pragma unroll
        for (int k = 0; k < DIN; ++k) {
            f2 xk = in[k];
#pragma unroll
            for (int o = ot; o < oe; ++o)
                out[o] = __builtin_elementwise_fma(
                    xk, splat(wt[(o - ot) * DIN + k]), out[o]);
        }
    }
}

// Same, accumulator starts at bias + skip (fuses the decoder skip-add).
template <int DIN, int DOUT, int WO, int BO>
DEV void lin2_skip(const f2* in, const f2* skip, f2* out) {
    const float* __restrict__ w =
        (const float*)__builtin_assume_aligned(&Wpack[WO], 16);
    const float* __restrict__ b = &Wpack[BO];
#pragma unroll
    for (int ot = 0; ot < DOUT; ot += 4) {
        const int oe = (ot + 4 < DOUT) ? (ot + 4) : DOUT;
        float wt[48];
#pragma unroll
        for (int i = 0; i < 48; ++i) {
            if (i < (oe - ot) * DIN) wt[i] = w[ot * DIN + i];
        }
#pragma unroll
        for (int o = ot; o < oe; ++o) out[o] = splat(b[o]) + skip[o];
#pragma unroll
        for (int k = 0; k < DIN; ++k) {
            f2 xk = in[k];
#pragma unroll
            for (int o = ot; o < oe; ++o)
                out[o] = __builtin_elementwise_fma(
                    xk, splat(wt[(o - ot) * DIN + k]), out[o]);
        }
    }
}

template <int N>
DEV void relu_ip(f2* v) {
#pragma unroll
    for (int k = 0; k < N; ++k) v[k] = __builtin_elementwise_max(v[k], splat(0.0f));
}

__global__ void __launch_bounds__(256, 2)
csnet14_kernel(const float* __restrict__ x, float* __restrict__ out, int nt) {
    int t = blockIdx.x * blockDim.x + threadIdx.x;
    if (t >= nt) return;  // nt = n/2 row-pairs

    // Two adjacent rows: 24 contiguous floats = 6x float4 (96 B).
    const float4* xr = reinterpret_cast<const float4*>(x + (size_t)t * 24);
    float4 a0 = xr[0], a1 = xr[1], a2 = xr[2];
    float4 a3 = xr[3], a4 = xr[4], a5 = xr[5];
    float r0[12] = {a0.x, a0.y, a0.z, a0.w, a1.x, a1.y, a1.z, a1.w,
                    a2.x, a2.y, a2.z, a2.w};
    float r1[12] = {a3.x, a3.y, a3.z, a3.w, a4.x, a4.y, a4.z, a4.w,
                    a5.x, a5.y, a5.z, a5.w};
    f2 h0[12];
#pragma unroll
    for (int k = 0; k < 12; ++k) { h0[k].x = r0[k]; h0[k].y = r1[k]; }

    // Encoder: fc1..fc6, save post-ReLU identities.
    f2 id1[12]; lin2<12, 12, OW1, OB1>(h0,  id1); relu_ip<12>(id1);
    f2 id2[11]; lin2<12, 11, OW2, OB2>(id1, id2); relu_ip<11>(id2);
    f2 id3[10]; lin2<11, 10, OW3, OB3>(id2, id3); relu_ip<10>(id3);
    f2 id4[9];  lin2<10,  9, OW4, OB4>(id3, id4); relu_ip<9>(id4);
    f2 id5[8];  lin2< 9,  8, OW5, OB5>(id4, id5); relu_ip<8>(id5);
    f2 id6[7];  lin2< 8,  7, OW6, OB6>(id5, id6); relu_ip<7>(id6);

    // Bottleneck fc7.
    f2 t7[6];   lin2< 7,  6, OW7, OB7>(id6, t7);  relu_ip<6>(t7);

    // Decoder: fc8..fc13, skip fused into accumulator init.
    f2 t8[7];   lin2_skip< 6,  7, OW8,  OB8 >(t7,  id6, t8);  relu_ip<7>(t8);
    f2 t9[8];   lin2_skip< 7,  8, OW9,  OB9 >(t8,  id5, t9);  relu_ip<8>(t9);
    f2 t10[9];  lin2_skip< 8,  9, OW10, OB10>(t9,  id4, t10); relu_ip<9>(t10);
    f2 t11[10]; lin2_skip< 9, 10, OW11, OB11>(t10, id3, t11); relu_ip<10>(t11);
    f2 t12[11]; lin2_skip<10, 11, OW12, OB12>(t11, id2, t12); relu_ip<11>(t12);
    f2 t13[12]; lin2_skip<11, 12, OW13, OB13>(t12, id1, t13); relu_ip<12>(t13);

    // fc14 (12 -> 2) + softmax, both rows.
    f2 l[2];    lin2<12,  2, OW14, OB14>(t13, l);
    f2 m  = __builtin_elementwise_max(l[0], l[1]);
    f2 d0 = l[0] - m;
    f2 d1 = l[1] - m;
    float e0a = __expf(d0.x), e0b = __expf(d0.y);
    float e1a = __expf(d1.x), e1b = __expf(d1.y);
    float inva = __builtin_amdgcn_rcpf(e0a + e1a);
    float invb = __builtin_amdgcn_rcpf(e0b + e1b);

    float4 o;  // rows 2t, 2t+1 -> out[4t..4t+3], coalesced 16 B/lane
    o.x = e0a * inva;
    o.y = e1a * inva;
    o.z = e0b * invb;
    o.w = e1b * invb;
    reinterpret_cast<float4*>(out)[t] = o;
}

extern "C" void kernel_launch(void* const* d_in, const int* in_sizes, int n_in,
                              void* d_out, int out_size, void* d_ws, size_t ws_size,
                              hipStream_t stream) {
    const float* x   = (const float*)d_in[0];
    const float* w1  = (const float*)d_in[1];  const float* b1  = (const float*)d_in[2];
    const float* w2  = (const float*)d_in[3];  const float* b2  = (const float*)d_in[4];
    const float* w3  = (const float*)d_in[5];  const float* b3  = (const float*)d_in[6];
    const float* w4  = (const float*)d_in[7];  const float* b4  = (const float*)d_in[8];
    const float* w5  = (const float*)d_in[9];  const float* b5  = (const float*)d_in[10];
    const float* w6  = (const float*)d_in[11]; const float* b6  = (const float*)d_in[12];
    const float* w7  = (const float*)d_in[13]; const float* b7  = (const float*)d_in[14];
    const float* w8  = (const float*)d_in[15]; const float* b8  = (const float*)d_in[16];
    const float* w9  = (const float*)d_in[17]; const float* b9  = (const float*)d_in[18];
    const float* w10 = (const float*)d_in[19]; const float* b10 = (const float*)d_in[20];
    const float* w11 = (const float*)d_in[21]; const float* b11 = (const float*)d_in[22];
    const float* w12 = (const float*)d_in[23]; const float* b12 = (const float*)d_in[24];
    const float* w13 = (const float*)d_in[25]; const float* b13 = (const float*)d_in[26];
    const float* w14 = (const float*)d_in[27]; const float* b14 = (const float*)d_in[28];
    float* out = (float*)d_out;

    const int n  = in_sizes[0] / 12;  // 2,000,000 rows (even)
    const int nt = n / 2;             // row-pairs

    // Stage 1: pack weights+biases into the single consumption-order buffer.
    repack_kernel<<<1, 256, 0, stream>>>(
        w1, b1, w2, b2, w3, b3, w4, b4, w5, b5, w6, b6, w7, b7,
        w8, b8, w9, b9, w10, b10, w11, b11, w12, b12, w13, b13, w14, b14);

    // Stage 2: main fused MLP.
    dim3 block(256);
    dim3 grid((nt + 255) / 256);
    csnet14_kernel<<<grid, block, 0, stream>>>(x, out, nt);
}

// Round 6
// 237.715 us; speedup vs baseline: 1.0008x; 1.0008x over previous
//
#include <hip/hip_runtime.h>
#include <math.h>

#define DEV __device__ __forceinline__

// Packed fp32 pair: .x = row A, .y = row B -> v_pk_fma_f32 (2 rows/inst).
typedef float f2 __attribute__((ext_vector_type(2)));
// Packed f16 pair for long-lived identity storage (1 reg per element-pair).
typedef _Float16 h2 __attribute__((ext_vector_type(2)));

DEV f2 splat(float s) { f2 r; r.x = s; r.y = s; return r; }

// RNE f32x2 -> f16x2 pack (v_cvt_f16_f32 x2 + pack; RNE, rel err 2^-11).
DEV h2 pk(f2 v) { h2 r; r.x = (_Float16)v.x; r.y = (_Float16)v.y; return r; }
DEV f2 unpk(h2 h) { f2 r; r.x = (float)h.x; r.y = (float)h.y; return r; }

// R6: shrink LIVE STATE, not the stream.
//
// R5 post-mortem: weight-stream fixes (R4 tile merge, R5 single base) bought
// only 75->66us combined; VALUBusy stuck ~60%. Occupancy evidence across all
// rounds: reported VGPR_Count is ARCH regs only; total = arch + AGPR-parked
// state ~= 160 (R0/R4/R5: 64+~96 -> 3 waves/SIMD 35%; R2: 36+~75 -> 57%;
// R3: 40+~68 -> 59%). Every variant is state-bound: the 57-f2 identity set
// (114 regs) dominates. 3 waves/SIMD cannot cover ~25k wait cyc/wave.
//
// R6 fix: park identities as PACKED F16 (RNE) right after each ReLU; the f32
// copy dies after feeding the next layer. Long-term state 114 -> 57 regs,
// total ~90-105 -> 4-5 waves/SIMD. Only skip values are rounded (once, RNE);
// all matmul math stays fp32. launch_bounds(256,4): 128-reg cap keeps the
// allocator in arch VGPRs (no AGPR shuttle — R1/R3's failure mode).

// Packed layout offsets (floats); every segment 4-float (16 B) aligned.
#define OW1  0
#define OB1  144
#define OW2  156
#define OB2  288
#define OW3  300
#define OB3  412
#define OW4  424
#define OB4  516
#define OW5  528
#define OB5  600
#define OW6  608
#define OB6  664
#define OW7  672
#define OB7  716
#define OW8  724
#define OB8  768
#define OW9  776
#define OB9  832
#define OW10 840
#define OB10 912
#define OW11 924
#define OB11 1016
#define OW12 1028
#define OB12 1140
#define OW13 1152
#define OB13 1284
#define OW14 1296
#define OB14 1320
#define WTOT 1324

__device__ __attribute__((aligned(16))) float Wpack[WTOT];

__global__ void repack_kernel(
    const float* w1,  const float* b1,  const float* w2,  const float* b2,
    const float* w3,  const float* b3,  const float* w4,  const float* b4,
    const float* w5,  const float* b5,  const float* w6,  const float* b6,
    const float* w7,  const float* b7,  const float* w8,  const float* b8,
    const float* w9,  const float* b9,  const float* w10, const float* b10,
    const float* w11, const float* b11, const float* w12, const float* b12,
    const float* w13, const float* b13, const float* w14, const float* b14) {
    struct Seg { const float* src; int dst; int len; };
    const Seg segs[28] = {
        {w1,  OW1,  144}, {b1,  OB1,  12}, {w2,  OW2,  132}, {b2,  OB2,  11},
        {w3,  OW3,  110}, {b3,  OB3,  10}, {w4,  OW4,   90}, {b4,  OB4,   9},
        {w5,  OW5,   72}, {b5,  OB5,   8}, {w6,  OW6,   56}, {b6,  OB6,   7},
        {w7,  OW7,   42}, {b7,  OB7,   6}, {w8,  OW8,   42}, {b8,  OB8,   7},
        {w9,  OW9,   56}, {b9,  OB9,   8}, {w10, OW10,  72}, {b10, OB10,  9},
        {w11, OW11,  90}, {b11, OB11, 10}, {w12, OW12, 110}, {b12, OB12, 11},
        {w13, OW13, 132}, {b13, OB13, 12}, {w14, OW14,  24}, {b14, OB14,  2}};
    const int tid = threadIdx.x;
    for (int s = 0; s < 28; ++s)
        for (int i = tid; i < segs[s].len; i += 256)
            Wpack[segs[s].dst + i] = segs[s].src[i];
}

// o-TILE (4 rows) + k-inner, weights from the packed stream (R4/R5 keep).
template <int DIN, int DOUT, int WO, int BO>
DEV void lin2(const f2* in, f2* out) {
    const float* __restrict__ w =
        (const float*)__builtin_assume_aligned(&Wpack[WO], 16);
    const float* __restrict__ b = &Wpack[BO];
#pragma unroll
    for (int ot = 0; ot < DOUT; ot += 4) {
        const int oe = (ot + 4 < DOUT) ? (ot + 4) : DOUT;
        float wt[48];
#pragma unroll
        for (int i = 0; i < 48; ++i) {
            if (i < (oe - ot) * DIN) wt[i] = w[ot * DIN + i];
        }
#pragma unroll
        for (int o = ot; o < oe; ++o) out[o] = splat(b[o]);
#pragma unroll
        for (int k = 0; k < DIN; ++k) {
            f2 xk = in[k];
#pragma unroll
            for (int o = ot; o < oe; ++o)
                out[o] = __builtin_elementwise_fma(
                    xk, splat(wt[(o - ot) * DIN + k]), out[o]);
        }
    }
}

// Skip variant: accumulator init = bias + f16-unpacked identity.
template <int DIN, int DOUT, int WO, int BO>
DEV void lin2_skip(const f2* in, const h2* skip, f2* out) {
    const float* __restrict__ w =
        (const float*)__builtin_assume_aligned(&Wpack[WO], 16);
    const float* __restrict__ b = &Wpack[BO];
#pragma unroll
    for (int ot = 0; ot < DOUT; ot += 4) {
        const int oe = (ot + 4 < DOUT) ? (ot + 4) : DOUT;
        float wt[48];
#pragma unroll
        for (int i = 0; i < 48; ++i) {
            if (i < (oe - ot) * DIN) wt[i] = w[ot * DIN + i];
        }
#pragma unroll
        for (int o = ot; o < oe; ++o) out[o] = splat(b[o]) + unpk(skip[o]);
#pragma unroll
        for (int k = 0; k < DIN; ++k) {
            f2 xk = in[k];
#pragma unroll
            for (int o = ot; o < oe; ++o)
                out[o] = __builtin_elementwise_fma(
                    xk, splat(wt[(o - ot) * DIN + k]), out[o]);
        }
    }
}

template <int N>
DEV void relu_ip(f2* v) {
#pragma unroll
    for (int k = 0; k < N; ++k) v[k] = __builtin_elementwise_max(v[k], splat(0.0f));
}

template <int N>
DEV void pack_id(const f2* v, h2* p) {
#pragma unroll
    for (int k = 0; k < N; ++k) p[k] = pk(v[k]);
}

__global__ void __launch_bounds__(256, 4)
csnet14_kernel(const float* __restrict__ x, float* __restrict__ out, int nt) {
    int t = blockIdx.x * blockDim.x + threadIdx.x;
    if (t >= nt) return;  // nt = n/2 row-pairs

    // Two adjacent rows: 24 contiguous floats = 6x float4 (96 B).
    const float4* xr = reinterpret_cast<const float4*>(x + (size_t)t * 24);
    float4 a0 = xr[0], a1 = xr[1], a2 = xr[2];
    float4 a3 = xr[3], a4 = xr[4], a5 = xr[5];
    float r0[12] = {a0.x, a0.y, a0.z, a0.w, a1.x, a1.y, a1.z, a1.w,
                    a2.x, a2.y, a2.z, a2.w};
    float r1[12] = {a3.x, a3.y, a3.z, a3.w, a4.x, a4.y, a4.z, a4.w,
                    a5.x, a5.y, a5.z, a5.w};
    f2 h0[12];
#pragma unroll
    for (int k = 0; k < 12; ++k) { h0[k].x = r0[k]; h0[k].y = r1[k]; }

    // Encoder: fc1..fc6. f32 copy feeds the next layer then dies; the
    // long-lived identity lives as packed f16 (1 reg / element-pair).
    f2 id1[12]; lin2<12, 12, OW1, OB1>(h0,  id1); relu_ip<12>(id1);
    h2 p1[12];  pack_id<12>(id1, p1);
    f2 id2[11]; lin2<12, 11, OW2, OB2>(id1, id2); relu_ip<11>(id2);
    h2 p2[11];  pack_id<11>(id2, p2);
    f2 id3[10]; lin2<11, 10, OW3, OB3>(id2, id3); relu_ip<10>(id3);
    h2 p3[10];  pack_id<10>(id3, p3);
    f2 id4[9];  lin2<10,  9, OW4, OB4>(id3, id4); relu_ip<9>(id4);
    h2 p4[9];   pack_id<9>(id4, p4);
    f2 id5[8];  lin2< 9,  8, OW5, OB5>(id4, id5); relu_ip<8>(id5);
    h2 p5[8];   pack_id<8>(id5, p5);
    f2 id6[7];  lin2< 8,  7, OW6, OB6>(id5, id6); relu_ip<7>(id6);
    h2 p6[7];   pack_id<7>(id6, p6);

    // Bottleneck fc7 (consumes f32 id6, which then dies).
    f2 t7[6];   lin2< 7,  6, OW7, OB7>(id6, t7);  relu_ip<6>(t7);

    // Decoder: fc8..fc13, skip unpacked f16 -> f32 in accumulator init.
    f2 t8[7];   lin2_skip< 6,  7, OW8,  OB8 >(t7,  p6, t8);  relu_ip<7>(t8);
    f2 t9[8];   lin2_skip< 7,  8, OW9,  OB9 >(t8,  p5, t9);  relu_ip<8>(t9);
    f2 t10[9];  lin2_skip< 8,  9, OW10, OB10>(t9,  p4, t10); relu_ip<9>(t10);
    f2 t11[10]; lin2_skip< 9, 10, OW11, OB11>(t10, p3, t11); relu_ip<10>(t11);
    f2 t12[11]; lin2_skip<10, 11, OW12, OB12>(t11, p2, t12); relu_ip<11>(t12);
    f2 t13[12]; lin2_skip<11, 12, OW13, OB13>(t12, p1, t13); relu_ip<12>(t13);

    // fc14 (12 -> 2) + softmax, both rows.
    f2 l[2];    lin2<12,  2, OW14, OB14>(t13, l);
    f2 m  = __builtin_elementwise_max(l[0], l[1]);
    f2 d0 = l[0] - m;
    f2 d1 = l[1] - m;
    float e0a = __expf(d0.x), e0b = __expf(d0.y);
    float e1a = __expf(d1.x), e1b = __expf(d1.y);
    float inva = __builtin_amdgcn_rcpf(e0a + e1a);
    float invb = __builtin_amdgcn_rcpf(e0b + e1b);

    float4 o;  // rows 2t, 2t+1 -> out[4t..4t+3], coalesced 16 B/lane
    o.x = e0a * inva;
    o.y = e1a * inva;
    o.z = e0b * invb;
    o.w = e1b * invb;
    reinterpret_cast<float4*>(out)[t] = o;
}

extern "C" void kernel_launch(void* const* d_in, const int* in_sizes, int n_in,
                              void* d_out, int out_size, void* d_ws, size_t ws_size,
                              hipStream_t stream) {
    const float* x   = (const float*)d_in[0];
    const float* w1  = (const float*)d_in[1];  const float* b1  = (const float*)d_in[2];
    const float* w2  = (const float*)d_in[3];  const float* b2  = (const float*)d_in[4];
    const float* w3  = (const float*)d_in[5];  const float* b3  = (const float*)d_in[6];
    const float* w4  = (const float*)d_in[7];  const float* b4  = (const float*)d_in[8];
    const float* w5  = (const float*)d_in[9];  const float* b5  = (const float*)d_in[10];
    const float* w6  = (const float*)d_in[11]; const float* b6  = (const float*)d_in[12];
    const float* w7  = (const float*)d_in[13]; const float* b7  = (const float*)d_in[14];
    const float* w8  = (const float*)d_in[15]; const float* b8  = (const float*)d_in[16];
    const float* w9  = (const float*)d_in[17]; const float* b9  = (const float*)d_in[18];
    const float* w10 = (const float*)d_in[19]; const float* b10 = (const float*)d_in[20];
    const float* w11 = (const float*)d_in[21]; const float* b11 = (const float*)d_in[22];
    const float* w12 = (const float*)d_in[23]; const float* b12 = (const float*)d_in[24];
    const float* w13 = (const float*)d_in[25]; const float* b13 = (const float*)d_in[26];
    const float* w14 = (const float*)d_in[27]; const float* b14 = (const float*)d_in[28];
    float* out = (float*)d_out;

    const int n  = in_sizes[0] / 12;  // 2,000,000 rows (even)
    const int nt = n / 2;             // row-pairs

    // Stage 1: pack weights+biases into the single consumption-order buffer.
    repack_kernel<<<1, 256, 0, stream>>>(
        w1, b1, w2, b2, w3, b3, w4, b4, w5, b5, w6, b6, w7, b7,
        w8, b8, w9, b9, w10, b10, w11, b11, w12, b12, w13, b13, w14, b14);

    // Stage 2: main fused MLP.
    dim3 block(256);
    dim3 grid((nt + 255) / 256);
    csnet14_kernel<<<grid, block, 0, stream>>>(x, out, nt);
}